// Round 9
// baseline (493.764 us; speedup 1.0000x reference)
//
#include <hip/hip_runtime.h>
#include <hip/hip_bf16.h>
#include <math.h>

#define MM 256
#define LL 4096
#define TT 2048

typedef __attribute__((ext_vector_type(8))) short bf16x8;
typedef __attribute__((ext_vector_type(4))) float f32x4;
typedef __attribute__((ext_vector_type(4))) unsigned short us4;
typedef unsigned short ushort_t;

// workspace float offsets
#define OFF_Q      262144
#define OFF_D      266240
#define OFF_CNT    270336   // 20 int counters (zeroed)
#define OFF_RINVP  290816
#define OFF_GP     421888
#define OFF_APL    552960
#define OFF_XPL    2650112
#define OFF_ATP    3698688
#define OFF_WTP    5795840
#define OFF_XA     9990144
#define OFF_XB     10121216
#define OFF_EA     10252288
#define OFF_EB     10383360
#define OFF_PA     10514432  // A-gram partials: 32*10*4096 f2
#define OFF_PX     13135872  // X-gram partials: 16*10*4096 f2

#define MFMA3(ACC, AH, AL, BH, BL)                                              \
  ACC = __builtin_amdgcn_mfma_f32_16x16x32_bf16(AH, BH, ACC, 0, 0, 0);          \
  ACC = __builtin_amdgcn_mfma_f32_16x16x32_bf16(AH, BL, ACC, 0, 0, 0);          \
  ACC = __builtin_amdgcn_mfma_f32_16x16x32_bf16(AL, BH, ACC, 0, 0, 0);

__device__ __forceinline__ void split_bf16(float x, ushort_t& h, ushort_t& l) {
  __hip_bfloat16 bh = __float2bfloat16(x);
  h = *(ushort_t*)&bh;
  __hip_bfloat16 bl = __float2bfloat16(x - __bfloat162float(bh));
  l = *(ushort_t*)&bl;
}
__device__ __forceinline__ float bfu2f(ushort_t u) {
  unsigned v = ((unsigned)u) << 16;
  float f;
  __builtin_memcpy(&f, &v, 4);
  return f;
}

// ---------------- reductions ----------------
__device__ __forceinline__ float wave_red_sum(float v) {
#pragma unroll
  for (int o = 32; o > 0; o >>= 1) v += __shfl_down(v, o);
  return v;
}
__device__ __forceinline__ float wave_red_max(float v) {
#pragma unroll
  for (int o = 32; o > 0; o >>= 1) v = fmaxf(v, __shfl_down(v, o));
  return v;
}
__device__ float blk_red_sum(float v) {
  __shared__ float sh[4];
  int lane = threadIdx.x & 63, wv = threadIdx.x >> 6;
  v = wave_red_sum(v);
  __syncthreads();
  if (lane == 0) sh[wv] = v;
  __syncthreads();
  return sh[0] + sh[1] + sh[2] + sh[3];
}
__device__ float blk_red_max(float v) {
  __shared__ float shm[4];
  int lane = threadIdx.x & 63, wv = threadIdx.x >> 6;
  v = wave_red_max(v);
  __syncthreads();
  if (lane == 0) shm[wv] = v;
  __syncthreads();
  return fmaxf(fmaxf(shm[0], shm[1]), fmaxf(shm[2], shm[3]));
}

// ---------------- prep: zero q/d/counters + A/X -> split-bf16 planes + A^T planes --------
// blocks: [0,33) zero; [33,1057) A conv; [1057,1569) X conv; [1569,2593) transpA
__global__ __launch_bounds__(256) void k_prep(float* __restrict__ ws,
                                              const float* __restrict__ Are,
                                              const float* __restrict__ Aim,
                                              const float* __restrict__ Xre,
                                              const float* __restrict__ Xim,
                                              const float* __restrict__ gamma) {
  __shared__ float tr[32][33], ti[32][33];
  int bid = blockIdx.x, tid = threadIdx.x;
  if (bid < 33) {                                  // zero q, d, counters
    ws[OFF_Q + bid * 256 + tid] = 0.0f;
  } else if (bid < 1057) {                         // A -> planes, sqrt(gamma) folded
    int i4 = (bid - 33) * 256 + tid;               // float4 index, 262144 total
    ushort_t* dst = (ushort_t*)(ws + OFF_APL);
    float4 re = ((const float4*)Are)[i4];
    float4 im = ((const float4*)Aim)[i4];
    float4 ga = ((const float4*)gamma)[i4 & (LL / 4 - 1)];
    float sr[4] = {re.x * sqrtf(ga.x), re.y * sqrtf(ga.y), re.z * sqrtf(ga.z), re.w * sqrtf(ga.w)};
    float si[4] = {im.x * sqrtf(ga.x), im.y * sqrtf(ga.y), im.z * sqrtf(ga.z), im.w * sqrtf(ga.w)};
    us4 hr, lr, hi, li;
#pragma unroll
    for (int e = 0; e < 4; ++e) {
      ushort_t h, l;
      split_bf16(sr[e], h, l); hr[e] = h; lr[e] = l;
      split_bf16(si[e], h, l); hi[e] = h; li[e] = l;
    }
    size_t o = (size_t)i4 * 4;
    *(us4*)(dst + o) = hr;
    *(us4*)(dst + (size_t)MM * LL + o) = lr;
    *(us4*)(dst + 2 * (size_t)MM * LL + o) = hi;
    *(us4*)(dst + 3 * (size_t)MM * LL + o) = li;
  } else if (bid < 1569) {                         // X -> planes
    int i4 = (bid - 1057) * 256 + tid;             // 131072 total
    ushort_t* dst = (ushort_t*)(ws + OFF_XPL);
    float4 re = ((const float4*)Xre)[i4];
    float4 im = ((const float4*)Xim)[i4];
    float fr[4] = {re.x, re.y, re.z, re.w};
    float fi[4] = {im.x, im.y, im.z, im.w};
    us4 hr, lr, hi, li;
#pragma unroll
    for (int e = 0; e < 4; ++e) {
      ushort_t h, l;
      split_bf16(fr[e], h, l); hr[e] = h; lr[e] = l;
      split_bf16(fi[e], h, l); hi[e] = h; li[e] = l;
    }
    size_t o = (size_t)i4 * 4;
    *(us4*)(dst + o) = hr;
    *(us4*)(dst + (size_t)MM * TT + o) = lr;
    *(us4*)(dst + 2 * (size_t)MM * TT + o) = hi;
    *(us4*)(dst + 3 * (size_t)MM * TT + o) = li;
  } else {                                         // transpA: [256][4096] -> planes [4096][256]
    int b2 = bid - 1569;
    ushort_t* dst = (ushort_t*)(ws + OFF_ATP);
    int c0 = (b2 & 127) * 32, r0 = (b2 >> 7) * 32;
    int tx = tid & 31, tg = tid >> 5;
#pragma unroll
    for (int i = 0; i < 4; ++i) {
      int r = tg + 8 * i;
      tr[r][tx] = Are[(size_t)(r0 + r) * LL + c0 + tx];
      ti[r][tx] = Aim[(size_t)(r0 + r) * LL + c0 + tx];
    }
    __syncthreads();
#pragma unroll
    for (int i = 0; i < 4; ++i) {
      int rr = tg + 8 * i;
      size_t o = (size_t)(c0 + rr) * 256 + r0 + tx;
      ushort_t h, l;
      split_bf16(tr[tx][rr], h, l);
      dst[o] = h;
      dst[o + 1048576] = l;
      split_bf16(ti[tx][rr], h, l);
      dst[o + 2097152] = h;
      dst[o + 3145728] = l;
    }
  }
}

// ---------------- gram v4: LDS-staged, Hermitian tiles, split-K partials + last-block reduce
// A-gram: blocks [0,320): tile=bid%10, ksplit=bid/10 (S=32, Kc=128) -> R fp32 (full, +ridge)
// X-gram: blocks [320,480): S=16, Kc=128 -> Gp split-bf16 planes directly (full mirror)
__global__ __launch_bounds__(256, 4) void k_gram_both(float* __restrict__ ws) {
  __shared__ __align__(16) ushort_t sA[4][64][40];
  __shared__ __align__(16) ushort_t sB[4][64][40];
  __shared__ int rflag;
  const int ti_lu[10] = {0, 1, 1, 2, 2, 2, 3, 3, 3, 3};
  const int tj_lu[10] = {0, 0, 1, 0, 1, 2, 0, 1, 2, 3};
  int bid = blockIdx.x;
  bool isA = bid < 320;
  int b2 = isA ? bid : bid - 320;
  const ushort_t* pl = (const ushort_t*)(ws + (isA ? OFF_APL : OFF_XPL));
  int K = isA ? LL : TT;
  size_t PS = (size_t)MM * K;
  int tile = b2 % 10, ksplit = b2 / 10;
  int S = isA ? 32 : 16;
  float2* Pbase = (float2*)(ws + (isA ? OFF_PA : OFF_PX));
  int kbeg = ksplit * 128;
  int i0 = ti_lu[tile] * 64, j0 = tj_lu[tile] * 64;
  bool diag = (i0 == j0);
  int tid = threadIdx.x;
  int lane = tid & 63, wv = tid >> 6;
  int srow = tid >> 2, sslot = tid & 3;
  int arow = wv * 16 + (lane & 15);
  int kq = (lane >> 4) * 8;
  f32x4 z = {0.f, 0.f, 0.f, 0.f};
  f32x4 Zrr[4], Zri[4], Zir[4], Zii[4];
#pragma unroll
  for (int s = 0; s < 4; ++s) { Zrr[s] = z; Zri[s] = z; Zir[s] = z; Zii[s] = z; }

  for (int chunk = 0; chunk < 4; ++chunk) {
    int k0 = kbeg + chunk * 32;
    __syncthreads();
#pragma unroll
    for (int p = 0; p < 4; ++p) {
      *(bf16x8*)&sA[p][srow][sslot * 8] =
          *(const bf16x8*)(pl + p * PS + (size_t)(i0 + srow) * K + k0 + sslot * 8);
      if (!diag)
        *(bf16x8*)&sB[p][srow][sslot * 8] =
            *(const bf16x8*)(pl + p * PS + (size_t)(j0 + srow) * K + k0 + sslot * 8);
    }
    __syncthreads();
    bf16x8 arh = *(const bf16x8*)&sA[0][arow][kq];
    bf16x8 arl = *(const bf16x8*)&sA[1][arow][kq];
    bf16x8 aih = *(const bf16x8*)&sA[2][arow][kq];
    bf16x8 ail = *(const bf16x8*)&sA[3][arow][kq];
    ushort_t(*bs)[64][40] = diag ? sA : sB;
#pragma unroll
    for (int s = 0; s < 4; ++s) {
      int brow = s * 16 + (lane & 15);
      bf16x8 brh = *(const bf16x8*)&bs[0][brow][kq];
      bf16x8 brl = *(const bf16x8*)&bs[1][brow][kq];
      bf16x8 bih = *(const bf16x8*)&bs[2][brow][kq];
      bf16x8 bil = *(const bf16x8*)&bs[3][brow][kq];
      MFMA3(Zrr[s], arh, arl, brh, brl);
      MFMA3(Zri[s], arh, arl, bih, bil);
      MFMA3(Zir[s], aih, ail, brh, brl);
      MFMA3(Zii[s], aih, ail, bih, bil);
    }
  }
  // write partial tile (non-atomic)
  float2* Pt = Pbase + ((size_t)ksplit * 10 + tile) * 4096;
#pragma unroll
  for (int s = 0; s < 4; ++s) {
    int lcol = s * 16 + (lane & 15);
#pragma unroll
    for (int r = 0; r < 4; ++r) {
      int lrow = wv * 16 + (lane >> 4) * 4 + r;
      float re = Zrr[s][r] + Zii[s][r];   // a * conj(b)
      float im = Zir[s][r] - Zri[s][r];
      Pt[lrow * 64 + lcol] = make_float2(re, im);
    }
  }
  // last-arriving block reduces this tile
  __threadfence();
  if (tid == 0) {
    int* cnt = (int*)(ws + OFF_CNT);
    int old = atomicAdd(&cnt[(isA ? 0 : 10) + tile], 1);
    rflag = (old == S - 1);
  }
  __syncthreads();
  if (!rflag) return;
  __threadfence();
  float2* Rc = (float2*)ws;
  ushort_t* Gp = (ushort_t*)(ws + OFF_GP);
  int e0 = tid * 16;
  for (int e = e0; e < e0 + 16; e += 2) {
    float4 acc = {0.f, 0.f, 0.f, 0.f};
    for (int s = 0; s < S; ++s) {
      float4 v = *(const float4*)&Pbase[((size_t)s * 10 + tile) * 4096 + e];
      acc.x += v.x; acc.y += v.y; acc.z += v.z; acc.w += v.w;
    }
    int li = e >> 6, lj = e & 63;
    int gi = i0 + li, gj = j0 + lj;
    if (isA) {
      if (diag && gi == gj) acc.x += 0.01f;
      if (diag && gi == gj + 1) acc.z += 0.01f;
      Rc[gi * 256 + gj] = make_float2(acc.x, acc.y);
      Rc[gi * 256 + gj + 1] = make_float2(acc.z, acc.w);
      if (!diag) {
        Rc[gj * 256 + gi] = make_float2(acc.x, -acc.y);
        Rc[(gj + 1) * 256 + gi] = make_float2(acc.z, -acc.w);
      }
    } else {
      ushort_t h, l;
      int idx = gi * 256 + gj;
      split_bf16(acc.x, h, l); Gp[idx] = h; Gp[idx + 65536] = l;
      split_bf16(acc.y, h, l); Gp[idx + 131072] = h; Gp[idx + 196608] = l;
      split_bf16(acc.z, h, l); Gp[idx + 1] = h; Gp[idx + 1 + 65536] = l;
      split_bf16(acc.w, h, l); Gp[idx + 1 + 131072] = h; Gp[idx + 1 + 196608] = l;
      if (!diag) {
        int m0 = gj * 256 + gi, m1 = (gj + 1) * 256 + gi;
        split_bf16(acc.x, h, l); Gp[m0] = h; Gp[m0 + 65536] = l;
        split_bf16(-acc.y, h, l); Gp[m0 + 131072] = h; Gp[m0 + 196608] = l;
        split_bf16(acc.z, h, l); Gp[m1] = h; Gp[m1 + 65536] = l;
        split_bf16(-acc.w, h, l); Gp[m1 + 131072] = h; Gp[m1 + 196608] = l;
      }
    }
  }
}

// ---------------- n1: E1 = E0^2 (E0 on-the-fly from full R) + X1 elementwise ----------
// blocks [0,256): E1 matmul tiles; [256,512): X1
__global__ __launch_bounds__(256) void k_n1(float* __restrict__ ws) {
  __shared__ float2 As[16][17], Bs[16][17];
  const float2* R = (const float2*)ws;
  int bid = blockIdx.x, tid = threadIdx.x;
  if (bid < 256) {  // E1 = E0 @ E0 -> EA
    float2* E1 = (float2*)(ws + OFF_EA);
    int i0 = (bid >> 4) * 16, j0 = (bid & 15) * 16;
    int tx = tid & 15, ty = tid >> 4;
    int rowA = i0 + ty;
    float DiA = R[rowA * 257].x;
    float accx = 0.f, accy = 0.f;
    for (int k0 = 0; k0 < 256; k0 += 16) {
      __syncthreads();
      {
        int c = k0 + tx;
        float2 r = R[rowA * 256 + c];
        float dl = (rowA == c) ? 1.0f : 0.0f;
        As[ty][tx] = make_float2(dl - r.x / DiA, -r.y / DiA);
      }
      {
        int rB = k0 + ty, c = j0 + tx;
        float DiB = R[rB * 257].x;
        float2 r = R[rB * 256 + c];
        float dl = (rB == c) ? 1.0f : 0.0f;
        Bs[ty][tx] = make_float2(dl - r.x / DiB, -r.y / DiB);
      }
      __syncthreads();
#pragma unroll
      for (int kk = 0; kk < 16; ++kk) {
        float2 a = As[ty][kk], bb = Bs[kk][tx];
        accx += a.x * bb.x - a.y * bb.y;
        accy += a.x * bb.y + a.y * bb.x;
      }
    }
    E1[rowA * 256 + j0 + tx] = make_float2(accx, accy);
  } else {  // X1 = (I + E0) D^-1  -> XA
    float2* X1 = (float2*)(ws + OFF_XA);
    int idx = (bid - 256) * 256 + tid;
    int i = idx >> 8, j = idx & 255;
    float Dii = R[i * 257].x;
    float Djj = R[j * 257].x;
    float2 r = R[i * 256 + j];
    float dl = (i == j) ? 1.0f : 0.0f;
    float ex = dl - r.x / Dii;
    float ey = -r.y / Dii;
    X1[idx] = make_float2((dl + ex) / Djj, ey / Djj);
  }
}

// ---------------- coupled Newton step ----------------
__global__ __launch_bounds__(256) void k_newt_step(const float2* __restrict__ Xin,
                                                   const float2* __restrict__ Ein,
                                                   float2* __restrict__ Xout,
                                                   float2* __restrict__ Eout, int xblocks) {
  __shared__ float2 As[16][17], Bs[16][17];
  int bid = blockIdx.x;
  bool isX = bid < xblocks;
  int b = isX ? bid : bid - xblocks;
  const float2* Bm = isX ? Xin : Ein;
  int i0 = (b >> 4) * 16, j0 = (b & 15) * 16;
  int tx = threadIdx.x & 15, ty = threadIdx.x >> 4;
  float accx = 0.f, accy = 0.f;
  for (int k0 = 0; k0 < 256; k0 += 16) {
    __syncthreads();
    As[ty][tx] = Ein[(i0 + ty) * 256 + k0 + tx];
    Bs[ty][tx] = Bm[(k0 + ty) * 256 + j0 + tx];
    __syncthreads();
#pragma unroll
    for (int kk = 0; kk < 16; ++kk) {
      float2 a = As[ty][kk], bb = Bs[kk][tx];
      accx += a.x * bb.x - a.y * bb.y;
      accy += a.x * bb.y + a.y * bb.x;
    }
  }
  int idx = (i0 + ty) * 256 + j0 + tx;
  if (isX) {
    float2 x = Xin[idx];
    Xout[idx] = make_float2(x.x + accx, x.y + accy);
  } else {
    Eout[idx] = make_float2(accx, accy);
  }
}

// ---------------- Newton final: X' = Xin + Ein@Xin -> split-bf16 planes ----------------
__global__ __launch_bounds__(256) void k_newt_fin(const float2* __restrict__ Xin,
                                                  const float2* __restrict__ Ein,
                                                  ushort_t* __restrict__ dst) {
  __shared__ float2 As[16][17], Bs[16][17];
  int b = blockIdx.x;
  int i0 = (b >> 4) * 16, j0 = (b & 15) * 16;
  int tx = threadIdx.x & 15, ty = threadIdx.x >> 4;
  float accx = 0.f, accy = 0.f;
  for (int k0 = 0; k0 < 256; k0 += 16) {
    __syncthreads();
    As[ty][tx] = Ein[(i0 + ty) * 256 + k0 + tx];
    Bs[ty][tx] = Xin[(k0 + ty) * 256 + j0 + tx];
    __syncthreads();
#pragma unroll
    for (int kk = 0; kk < 16; ++kk) {
      float2 a = As[ty][kk], bb = Bs[kk][tx];
      accx += a.x * bb.x - a.y * bb.y;
      accy += a.x * bb.y + a.y * bb.x;
    }
  }
  int idx = (i0 + ty) * 256 + j0 + tx;
  float2 x = Xin[idx];
  float vx = x.x + accx, vy = x.y + accy;
  ushort_t h, l;
  split_bf16(vx, h, l);
  dst[idx] = h;
  dst[idx + 65536] = l;
  split_bf16(vy, h, l);
  dst[idx + 131072] = h;
  dst[idx + 196608] = l;
}

// ---------------- wide MFMA (B LDS-staged): (256x256) @ (256x4096) ----------------
__global__ __launch_bounds__(256) void k_wide_mfma(const ushort_t* __restrict__ Ap,
                                                   const ushort_t* __restrict__ Bp,
                                                   const float* __restrict__ AuxRe,
                                                   const float* __restrict__ AuxIm,
                                                   ushort_t* __restrict__ WTout,
                                                   float* __restrict__ dq, int mode) {
  __shared__ __align__(16) ushort_t sB[4][64][40];
  const ushort_t* arh_p = Ap;
  const ushort_t* arl_p = Ap + 65536;
  const ushort_t* aih_p = Ap + 131072;
  const ushort_t* ail_p = Ap + 196608;
  const ushort_t* brh_p = Bp;
  const ushort_t* brl_p = Bp + 1048576;
  const ushort_t* bih_p = Bp + 2097152;
  const ushort_t* bil_p = Bp + 3145728;
  int j0 = blockIdx.x * 64;  // l
  int i0 = blockIdx.y * 64;  // m
  int tid = threadIdx.x;
  int lane = tid & 63, wv = tid >> 6;
  int srow = tid >> 2, sslot = tid & 3;
  int m = i0 + wv * 16 + (lane & 15);
  int kq = (lane >> 4) * 8;
  f32x4 z = {0.f, 0.f, 0.f, 0.f};
  f32x4 Zrr[4], Zri[4], Zir[4], Zii[4];
#pragma unroll
  for (int s = 0; s < 4; ++s) { Zrr[s] = z; Zri[s] = z; Zir[s] = z; Zii[s] = z; }
  for (int k0 = 0; k0 < 256; k0 += 32) {
    __syncthreads();
    {
      size_t bo = (size_t)(j0 + srow) * 256 + k0 + sslot * 8;
      *(bf16x8*)&sB[0][srow][sslot * 8] = *(const bf16x8*)(brh_p + bo);
      *(bf16x8*)&sB[1][srow][sslot * 8] = *(const bf16x8*)(brl_p + bo);
      *(bf16x8*)&sB[2][srow][sslot * 8] = *(const bf16x8*)(bih_p + bo);
      *(bf16x8*)&sB[3][srow][sslot * 8] = *(const bf16x8*)(bil_p + bo);
    }
    __syncthreads();
    size_t ao = (size_t)m * 256 + k0 + kq;
    bf16x8 arh = *(const bf16x8*)(arh_p + ao);
    bf16x8 arl = *(const bf16x8*)(arl_p + ao);
    bf16x8 aih = *(const bf16x8*)(aih_p + ao);
    bf16x8 ail = *(const bf16x8*)(ail_p + ao);
#pragma unroll
    for (int s = 0; s < 4; ++s) {
      int brow = s * 16 + (lane & 15);
      bf16x8 brh = *(const bf16x8*)&sB[0][brow][kq];
      bf16x8 brl = *(const bf16x8*)&sB[1][brow][kq];
      bf16x8 bih = *(const bf16x8*)&sB[2][brow][kq];
      bf16x8 bil = *(const bf16x8*)&sB[3][brow][kq];
      MFMA3(Zrr[s], arh, arl, brh, brl);
      MFMA3(Zri[s], arh, arl, bih, bil);
      MFMA3(Zir[s], aih, ail, brh, brl);
      MFMA3(Zii[s], aih, ail, bih, bil);
    }
  }
  int rbase = i0 + wv * 16 + (lane >> 4) * 4;
#pragma unroll
  for (int s = 0; s < 4; ++s) {
    int col = j0 + s * 16 + (lane & 15);
    size_t wo = (size_t)col * 256 + rbase;
    float part = 0.f;
    if (mode == 0) {
      us4 hr, lr, hi, li;
#pragma unroll
      for (int r = 0; r < 4; ++r) {
        float re = Zrr[s][r] - Zii[s][r];   // a * b
        float im = Zri[s][r] + Zir[s][r];
        ushort_t h, l;
        split_bf16(re, h, l);
        hr[r] = h; lr[r] = l;
        split_bf16(im, h, l);
        hi[r] = h; li[r] = l;
        size_t o = (size_t)(rbase + r) * LL + col;
        part += re * AuxRe[o] - im * AuxIm[o];
      }
      *(us4*)(WTout + wo) = hr;
      *(us4*)(WTout + 1048576 + wo) = lr;
      *(us4*)(WTout + 2097152 + wo) = hi;
      *(us4*)(WTout + 3145728 + wo) = li;
    } else {
      us4 wh = *(const us4*)(brh_p + wo);
      us4 wl = *(const us4*)(brl_p + wo);
      us4 wih = *(const us4*)(bih_p + wo);
      us4 wil = *(const us4*)(bil_p + wo);
#pragma unroll
      for (int r = 0; r < 4; ++r) {
        float re = Zrr[s][r] - Zii[s][r];
        float im = Zri[s][r] + Zir[s][r];
        float wx = bfu2f(wh[r]) + bfu2f(wl[r]);
        float wy = bfu2f(wih[r]) + bfu2f(wil[r]);
        part += wx * re + wy * im;
      }
    }
    part += __shfl_down(part, 32);
    part += __shfl_down(part, 16);
    if ((lane >> 4) == 0) atomicAdd(dq + col, part);
  }
}

// ---------------- fused: per-row LN-stats recompute + gate + attention + combine --------
__global__ __launch_bounds__(256) void k_gateattn(const float* __restrict__ ws,
                                                  const float* __restrict__ Wg,
                                                  const float* __restrict__ gb,
                                                  const float* __restrict__ inw,
                                                  const float* __restrict__ inb,
                                                  const float* __restrict__ outw,
                                                  const float* __restrict__ outb,
                                                  const float* __restrict__ gamma,
                                                  const float* __restrict__ delta,
                                                  const float* __restrict__ lnw,
                                                  const float* __restrict__ lnb,
                                                  const float* __restrict__ lmbda,
                                                  float* __restrict__ out) {
  const float4* q4 = (const float4*)(ws + OFF_Q);
  const float4* d4 = (const float4*)(ws + OFF_D);
  const float4* g4 = (const float4*)gamma;
  const float4* lw4 = (const float4*)lnw;
  const float4* lb4 = (const float4*)lnb;
  int i = blockIdx.x, tid = threadIdx.x;
  float dlt = 1.0f / (1.0f + expf(-delta[0]));
  // pass 1: mean of u
  float s = 0.f;
  for (int j = tid; j < LL / 4; j += 256) {
    float4 qv = q4[j], dv = d4[j], pv = g4[j];
    s += pv.x + dlt * (qv.x / (dv.x + 1e-12f) - pv.x);
    s += pv.y + dlt * (qv.y / (dv.y + 1e-12f) - pv.y);
    s += pv.z + dlt * (qv.z / (dv.z + 1e-12f) - pv.z);
    s += pv.w + dlt * (qv.w / (dv.w + 1e-12f) - pv.w);
  }
  float mu = blk_red_sum(s) * (1.0f / LL);
  // pass 2: variance
  float s2 = 0.f;
  for (int j = tid; j < LL / 4; j += 256) {
    float4 qv = q4[j], dv = d4[j], pv = g4[j];
    float u0 = pv.x + dlt * (qv.x / (dv.x + 1e-12f) - pv.x) - mu;
    float u1 = pv.y + dlt * (qv.y / (dv.y + 1e-12f) - pv.y) - mu;
    float u2 = pv.z + dlt * (qv.z / (dv.z + 1e-12f) - pv.z) - mu;
    float u3 = pv.w + dlt * (qv.w / (dv.w + 1e-12f) - pv.w) - mu;
    s2 += u0 * u0 + u1 * u1 + u2 * u2 + u3 * u3;
  }
  float var = blk_red_sum(s2) * (1.0f / LL);
  float inv = rsqrtf(var + 1e-5f);
  // own row values
  const float* qs = ws + OFF_Q;
  const float* ds = ws + OFF_D;
  float v_i = qs[i] / (ds[i] + 1e-12f);
  float u_i = gamma[i] + dlt * (v_i - gamma[i]);
  float up_i = (u_i - mu) * inv * lnw[i] + lnb[i];
  float qvv = up_i * inw[0] + inb[0];
  float w1 = inw[1], b1 = inb[1], w2 = inw[2], b2 = inb[2];
  // pass 3: gate dot (u) + attn max (up)
  const float4* wr = (const float4*)(Wg + (size_t)i * LL);
  float sdot = 0.f, mx = -3.4e38f;
  for (int j = tid; j < LL / 4; j += 256) {
    float4 qv = q4[j], dv = d4[j], pv = g4[j], w = wr[j], lwv = lw4[j], lbv = lb4[j];
    float u0 = pv.x + dlt * (qv.x / (dv.x + 1e-12f) - pv.x);
    float u1 = pv.y + dlt * (qv.y / (dv.y + 1e-12f) - pv.y);
    float u2 = pv.z + dlt * (qv.z / (dv.z + 1e-12f) - pv.z);
    float u3 = pv.w + dlt * (qv.w / (dv.w + 1e-12f) - pv.w);
    sdot += w.x * u0 + w.y * u1 + w.z * u2 + w.w * u3;
    float k0 = ((u0 - mu) * inv * lwv.x + lbv.x) * w1 + b1;
    float k1 = ((u1 - mu) * inv * lwv.y + lbv.y) * w1 + b1;
    float k2 = ((u2 - mu) * inv * lwv.z + lbv.z) * w1 + b1;
    float k3 = ((u3 - mu) * inv * lwv.w + lbv.w) * w1 + b1;
    mx = fmaxf(mx, fmaxf(fmaxf(qvv * k0, qvv * k1), fmaxf(qvv * k2, qvv * k3)));
  }
  float tot = blk_red_sum(sdot);
  mx = blk_red_max(mx);
  float g = 1.0f / (1.0f + expf(-(tot + gb[i])));
  // pass 4: softmax num/den
  float den = 0.f, num = 0.f;
  for (int j = tid; j < LL / 4; j += 256) {
    float4 qv = q4[j], dv = d4[j], pv = g4[j], lwv = lw4[j], lbv = lb4[j];
    float u0 = pv.x + dlt * (qv.x / (dv.x + 1e-12f) - pv.x);
    float u1 = pv.y + dlt * (qv.y / (dv.y + 1e-12f) - pv.y);
    float u2 = pv.z + dlt * (qv.z / (dv.z + 1e-12f) - pv.z);
    float u3 = pv.w + dlt * (qv.w / (dv.w + 1e-12f) - pv.w);
    float p0 = (u0 - mu) * inv * lwv.x + lbv.x;
    float p1 = (u1 - mu) * inv * lwv.y + lbv.y;
    float p2 = (u2 - mu) * inv * lwv.z + lbv.z;
    float p3 = (u3 - mu) * inv * lwv.w + lbv.w;
    float e0 = expf(qvv * (p0 * w1 + b1) - mx);
    float e1 = expf(qvv * (p1 * w1 + b1) - mx);
    float e2 = expf(qvv * (p2 * w1 + b1) - mx);
    float e3 = expf(qvv * (p3 * w1 + b1) - mx);
    den += e0 + e1 + e2 + e3;
    num += e0 * (p0 * w2 + b2) + e1 * (p1 * w2 + b2) + e2 * (p2 * w2 + b2) + e3 * (p3 * w2 + b2);
  }
  den = blk_red_sum(den);
  num = blk_red_sum(num);
  if (tid == 0) {
    float attn = (num / den) * outw[0] + outb[0];
    float r = g * v_i + (1.0f - g) * gamma[i] + attn - lmbda[0];
    out[i] = fmaxf(r, 0.0f);
  }
}

extern "C" void kernel_launch(void* const* d_in, const int* in_sizes, int n_in,
                              void* d_out, int out_size, void* d_ws, size_t ws_size,
                              hipStream_t stream) {
  const float* gamma = (const float*)d_in[0];
  const float* Are   = (const float*)d_in[1];
  const float* Aim   = (const float*)d_in[2];
  const float* Xre   = (const float*)d_in[3];
  const float* Xim   = (const float*)d_in[4];
  const float* lnw   = (const float*)d_in[5];
  const float* lnb   = (const float*)d_in[6];
  const float* inw   = (const float*)d_in[7];
  const float* inb   = (const float*)d_in[8];
  const float* outw  = (const float*)d_in[9];
  const float* outb  = (const float*)d_in[10];
  const float* gateW = (const float*)d_in[11];
  const float* gateb = (const float*)d_in[12];
  const float* delta = (const float*)d_in[13];
  const float* lmbda = (const float*)d_in[14];
  float* out = (float*)d_out;
  float* ws = (float*)d_ws;

  float2* XA = (float2*)(ws + OFF_XA);
  float2* XB = (float2*)(ws + OFF_XB);
  float2* EA = (float2*)(ws + OFF_EA);
  float2* EB = (float2*)(ws + OFF_EB);
  ushort_t* Rinvp = (ushort_t*)(ws + OFF_RINVP);

  k_prep<<<2593, 256, 0, stream>>>(ws, Are, Aim, Xre, Xim, gamma);
  k_gram_both<<<480, 256, 0, stream>>>(ws);
  k_n1<<<512, 256, 0, stream>>>(ws);
  k_newt_step<<<512, 256, 0, stream>>>(XA, EA, XB, EB, 256);      // X2, E2=E0^4
  k_newt_step<<<512, 256, 0, stream>>>(XB, EB, XA, EA, 256);      // X3, E3=E0^8
  k_newt_step<<<512, 256, 0, stream>>>(XA, EA, XB, EB, 256);      // X4, E4=E0^16
  k_newt_fin<<<256, 256, 0, stream>>>(XB, EB, Rinvp);             // X5 -> planes

  k_wide_mfma<<<dim3(64, 4), 256, 0, stream>>>(Rinvp, (ushort_t*)(ws + OFF_ATP),
                                               Are, Aim, (ushort_t*)(ws + OFF_WTP),
                                               ws + OFF_D, 0);
  k_wide_mfma<<<dim3(64, 4), 256, 0, stream>>>((ushort_t*)(ws + OFF_GP),
                                               (ushort_t*)(ws + OFF_WTP),
                                               nullptr, nullptr, nullptr, ws + OFF_Q, 1);
  k_gateattn<<<LL, 256, 0, stream>>>(ws, gateW, gateb, inw, inb, outw, outb,
                                     gamma, delta, lnw, lnb, lmbda, out);
}

// Round 10
// 329.834 us; speedup vs baseline: 1.4970x; 1.4970x over previous
//
#include <hip/hip_runtime.h>
#include <hip/hip_bf16.h>
#include <math.h>

#define MM 256
#define LL 4096
#define TT 2048

typedef __attribute__((ext_vector_type(8))) short bf16x8;
typedef __attribute__((ext_vector_type(4))) float f32x4;
typedef __attribute__((ext_vector_type(4))) unsigned short us4;
typedef unsigned short ushort_t;

// workspace float offsets
#define OFF_G      131072
#define OFF_Q      262144
#define OFF_D      266240
#define ZERO_FL    270336   // zero range [0, ZERO_FL): R, G, q, d
#define OFF_RINVP  290816
#define OFF_GP     421888
#define OFF_APL    552960
#define OFF_XPL    2650112
#define OFF_ATP    3698688
#define OFF_WTP    5795840
#define OFF_XA     9990144
#define OFF_XB     10121216
#define OFF_EA     10252288
#define OFF_EB     10383360

#define MFMA3(ACC, AH, AL, BH, BL)                                              \
  ACC = __builtin_amdgcn_mfma_f32_16x16x32_bf16(AH, BH, ACC, 0, 0, 0);          \
  ACC = __builtin_amdgcn_mfma_f32_16x16x32_bf16(AH, BL, ACC, 0, 0, 0);          \
  ACC = __builtin_amdgcn_mfma_f32_16x16x32_bf16(AL, BH, ACC, 0, 0, 0);

__device__ __forceinline__ void split_bf16(float x, ushort_t& h, ushort_t& l) {
  __hip_bfloat16 bh = __float2bfloat16(x);
  h = *(ushort_t*)&bh;
  __hip_bfloat16 bl = __float2bfloat16(x - __bfloat162float(bh));
  l = *(ushort_t*)&bl;
}
__device__ __forceinline__ float bfu2f(ushort_t u) {
  unsigned v = ((unsigned)u) << 16;
  float f;
  __builtin_memcpy(&f, &v, 4);
  return f;
}

// ---------------- reductions ----------------
__device__ __forceinline__ float wave_red_sum(float v) {
#pragma unroll
  for (int o = 32; o > 0; o >>= 1) v += __shfl_down(v, o);
  return v;
}
__device__ __forceinline__ float wave_red_max(float v) {
#pragma unroll
  for (int o = 32; o > 0; o >>= 1) v = fmaxf(v, __shfl_down(v, o));
  return v;
}
__device__ float blk_red_sum(float v) {
  __shared__ float sh[4];
  int lane = threadIdx.x & 63, wv = threadIdx.x >> 6;
  v = wave_red_sum(v);
  __syncthreads();
  if (lane == 0) sh[wv] = v;
  __syncthreads();
  return sh[0] + sh[1] + sh[2] + sh[3];
}
__device__ float blk_red_max(float v) {
  __shared__ float shm[4];
  int lane = threadIdx.x & 63, wv = threadIdx.x >> 6;
  v = wave_red_max(v);
  __syncthreads();
  if (lane == 0) shm[wv] = v;
  __syncthreads();
  return fmaxf(fmaxf(shm[0], shm[1]), fmaxf(shm[2], shm[3]));
}

// mirrored element (lower tiles valid; upper = conj of mirror)
__device__ __forceinline__ float2 r_mirror(const float2* __restrict__ R, int i, int j) {
  if ((i >> 6) >= (j >> 6)) return R[i * 256 + j];
  float2 r = R[j * 256 + i];
  r.y = -r.y;
  return r;
}

// ---------------- prep: zero R/G/q/d + A/X -> split-bf16 planes + A^T planes ------------
// blocks: [0,1056) zero; [1056,2080) A conv; [2080,2592) X conv; [2592,3616) transpA
__global__ __launch_bounds__(256) void k_prep(float* __restrict__ ws,
                                              const float* __restrict__ Are,
                                              const float* __restrict__ Aim,
                                              const float* __restrict__ Xre,
                                              const float* __restrict__ Xim,
                                              const float* __restrict__ gamma) {
  __shared__ float tr[32][33], ti[32][33];
  int bid = blockIdx.x, tid = threadIdx.x;
  if (bid < 1056) {                                // zero R,G,q,d (ridge on R diag)
    int idx = bid * 256 + tid;
    float v = 0.0f;
    if (idx < 131072 && (idx % 514) == 0) v = 0.01f;
    ws[idx] = v;
  } else if (bid < 2080) {                         // A -> planes, sqrt(gamma) folded
    int i4 = (bid - 1056) * 256 + tid;             // float4 index, 262144 total
    ushort_t* dst = (ushort_t*)(ws + OFF_APL);
    float4 re = ((const float4*)Are)[i4];
    float4 im = ((const float4*)Aim)[i4];
    float4 ga = ((const float4*)gamma)[i4 & (LL / 4 - 1)];
    float sr[4] = {re.x * sqrtf(ga.x), re.y * sqrtf(ga.y), re.z * sqrtf(ga.z), re.w * sqrtf(ga.w)};
    float si[4] = {im.x * sqrtf(ga.x), im.y * sqrtf(ga.y), im.z * sqrtf(ga.z), im.w * sqrtf(ga.w)};
    us4 hr, lr, hi, li;
#pragma unroll
    for (int e = 0; e < 4; ++e) {
      ushort_t h, l;
      split_bf16(sr[e], h, l); hr[e] = h; lr[e] = l;
      split_bf16(si[e], h, l); hi[e] = h; li[e] = l;
    }
    size_t o = (size_t)i4 * 4;
    *(us4*)(dst + o) = hr;
    *(us4*)(dst + (size_t)MM * LL + o) = lr;
    *(us4*)(dst + 2 * (size_t)MM * LL + o) = hi;
    *(us4*)(dst + 3 * (size_t)MM * LL + o) = li;
  } else if (bid < 2592) {                         // X -> planes
    int i4 = (bid - 2080) * 256 + tid;             // 131072 total
    ushort_t* dst = (ushort_t*)(ws + OFF_XPL);
    float4 re = ((const float4*)Xre)[i4];
    float4 im = ((const float4*)Xim)[i4];
    float fr[4] = {re.x, re.y, re.z, re.w};
    float fi[4] = {im.x, im.y, im.z, im.w};
    us4 hr, lr, hi, li;
#pragma unroll
    for (int e = 0; e < 4; ++e) {
      ushort_t h, l;
      split_bf16(fr[e], h, l); hr[e] = h; lr[e] = l;
      split_bf16(fi[e], h, l); hi[e] = h; li[e] = l;
    }
    size_t o = (size_t)i4 * 4;
    *(us4*)(dst + o) = hr;
    *(us4*)(dst + (size_t)MM * TT + o) = lr;
    *(us4*)(dst + 2 * (size_t)MM * TT + o) = hi;
    *(us4*)(dst + 3 * (size_t)MM * TT + o) = li;
  } else {                                         // transpA: [256][4096] -> planes [4096][256]
    int b2 = bid - 2592;
    ushort_t* dst = (ushort_t*)(ws + OFF_ATP);
    int c0 = (b2 & 127) * 32, r0 = (b2 >> 7) * 32;
    int tx = tid & 31, tg = tid >> 5;
#pragma unroll
    for (int i = 0; i < 4; ++i) {
      int r = tg + 8 * i;
      tr[r][tx] = Are[(size_t)(r0 + r) * LL + c0 + tx];
      ti[r][tx] = Aim[(size_t)(r0 + r) * LL + c0 + tx];
    }
    __syncthreads();
#pragma unroll
    for (int i = 0; i < 4; ++i) {
      int rr = tg + 8 * i;
      size_t o = (size_t)(c0 + rr) * 256 + r0 + tx;
      ushort_t h, l;
      split_bf16(tr[tx][rr], h, l);
      dst[o] = h;
      dst[o + 1048576] = l;
      split_bf16(ti[tx][rr], h, l);
      dst[o + 2097152] = h;
      dst[o + 3145728] = l;
    }
  }
}

// ---------------- gram v3 (PROVEN): LDS-staged, Hermitian lower tiles, fp32 atomics -----
__global__ __launch_bounds__(256, 4) void k_gram_both(float* __restrict__ ws) {
  __shared__ __align__(16) ushort_t sA[4][64][40];
  __shared__ __align__(16) ushort_t sB[4][64][40];
  const int ti_lu[10] = {0, 1, 1, 2, 2, 2, 3, 3, 3, 3};
  const int tj_lu[10] = {0, 0, 1, 0, 1, 2, 0, 1, 2, 3};
  int bid = blockIdx.x;
  const ushort_t* pl;
  float* C;
  int K, tile, ksplit;
  size_t PS;
  if (bid < 320) {
    pl = (const ushort_t*)(ws + OFF_APL);
    C = ws;
    K = LL;
    PS = (size_t)MM * LL;
    tile = bid % 10;
    ksplit = bid / 10;
  } else {
    int b2 = bid - 320;
    pl = (const ushort_t*)(ws + OFF_XPL);
    C = ws + OFF_G;
    K = TT;
    PS = (size_t)MM * TT;
    tile = b2 % 10;
    ksplit = b2 / 10;
  }
  int kbeg = ksplit * 128;
  int i0 = ti_lu[tile] * 64, j0 = tj_lu[tile] * 64;
  bool diag = (i0 == j0);
  int tid = threadIdx.x;
  int lane = tid & 63, wv = tid >> 6;
  int srow = tid >> 2, sslot = tid & 3;
  int arow = wv * 16 + (lane & 15);
  int kq = (lane >> 4) * 8;
  f32x4 z = {0.f, 0.f, 0.f, 0.f};
  f32x4 Zrr[4], Zri[4], Zir[4], Zii[4];
#pragma unroll
  for (int s = 0; s < 4; ++s) { Zrr[s] = z; Zri[s] = z; Zir[s] = z; Zii[s] = z; }

  for (int chunk = 0; chunk < 4; ++chunk) {
    int k0 = kbeg + chunk * 32;
    __syncthreads();
#pragma unroll
    for (int p = 0; p < 4; ++p) {
      *(bf16x8*)&sA[p][srow][sslot * 8] =
          *(const bf16x8*)(pl + p * PS + (size_t)(i0 + srow) * K + k0 + sslot * 8);
      if (!diag)
        *(bf16x8*)&sB[p][srow][sslot * 8] =
            *(const bf16x8*)(pl + p * PS + (size_t)(j0 + srow) * K + k0 + sslot * 8);
    }
    __syncthreads();
    bf16x8 arh = *(const bf16x8*)&sA[0][arow][kq];
    bf16x8 arl = *(const bf16x8*)&sA[1][arow][kq];
    bf16x8 aih = *(const bf16x8*)&sA[2][arow][kq];
    bf16x8 ail = *(const bf16x8*)&sA[3][arow][kq];
    ushort_t(*bs)[64][40] = diag ? sA : sB;
#pragma unroll
    for (int s = 0; s < 4; ++s) {
      int brow = s * 16 + (lane & 15);
      bf16x8 brh = *(const bf16x8*)&bs[0][brow][kq];
      bf16x8 brl = *(const bf16x8*)&bs[1][brow][kq];
      bf16x8 bih = *(const bf16x8*)&bs[2][brow][kq];
      bf16x8 bil = *(const bf16x8*)&bs[3][brow][kq];
      MFMA3(Zrr[s], arh, arl, brh, brl);
      MFMA3(Zri[s], arh, arl, bih, bil);
      MFMA3(Zir[s], aih, ail, brh, brl);
      MFMA3(Zii[s], aih, ail, bih, bil);
    }
  }
  int rbase = i0 + wv * 16 + (lane >> 4) * 4;
#pragma unroll
  for (int s = 0; s < 4; ++s) {
    int col = j0 + s * 16 + (lane & 15);
#pragma unroll
    for (int r = 0; r < 4; ++r) {
      float re = Zrr[s][r] + Zii[s][r];   // a * conj(b)
      float im = Zir[s][r] - Zri[s][r];
      float* p = C + ((size_t)(rbase + r) * 256 + col) * 2;
      atomicAdd(p, re);
      atomicAdd(p + 1, im);
    }
  }
}

// ---------------- n1: E1 = E0^2 (E0 on-the-fly, mirrored R) + X1 + G -> Gp --------------
// blocks [0,256): E1 matmul tiles; [256,512): X1; [512,768): Gp conversion
__global__ __launch_bounds__(256) void k_n1(float* __restrict__ ws) {
  __shared__ float2 As[16][17], Bs[16][17];
  const float2* R = (const float2*)ws;
  int bid = blockIdx.x, tid = threadIdx.x;
  if (bid < 256) {  // E1 = E0 @ E0 -> EA
    float2* E1 = (float2*)(ws + OFF_EA);
    int i0 = (bid >> 4) * 16, j0 = (bid & 15) * 16;
    int tx = tid & 15, ty = tid >> 4;
    int rowA = i0 + ty;
    float DiA = R[rowA * 257].x;
    float accx = 0.f, accy = 0.f;
    for (int k0 = 0; k0 < 256; k0 += 16) {
      __syncthreads();
      {
        int c = k0 + tx;
        float2 r = r_mirror(R, rowA, c);
        float dl = (rowA == c) ? 1.0f : 0.0f;
        As[ty][tx] = make_float2(dl - r.x / DiA, -r.y / DiA);
      }
      {
        int rB = k0 + ty, c = j0 + tx;
        float DiB = R[rB * 257].x;
        float2 r = r_mirror(R, rB, c);
        float dl = (rB == c) ? 1.0f : 0.0f;
        Bs[ty][tx] = make_float2(dl - r.x / DiB, -r.y / DiB);
      }
      __syncthreads();
#pragma unroll
      for (int kk = 0; kk < 16; ++kk) {
        float2 a = As[ty][kk], bb = Bs[kk][tx];
        accx += a.x * bb.x - a.y * bb.y;
        accy += a.x * bb.y + a.y * bb.x;
      }
    }
    E1[rowA * 256 + j0 + tx] = make_float2(accx, accy);
  } else if (bid < 512) {  // X1 = (I + E0) D^-1  -> XA
    float2* X1 = (float2*)(ws + OFF_XA);
    int idx = (bid - 256) * 256 + tid;
    int i = idx >> 8, j = idx & 255;
    float Dii = R[i * 257].x;
    float Djj = R[j * 257].x;
    float2 r = r_mirror(R, i, j);
    float dl = (i == j) ? 1.0f : 0.0f;
    float ex = dl - r.x / Dii;
    float ey = -r.y / Dii;
    X1[idx] = make_float2((dl + ex) / Djj, ey / Djj);
  } else {  // G -> Gp (Hermitian mirror)
    const float2* src = (const float2*)(ws + OFF_G);
    ushort_t* dst = (ushort_t*)(ws + OFF_GP);
    int idx = (bid - 512) * 256 + tid;
    int i = idx >> 8, j = idx & 255;
    float2 v = r_mirror(src, i, j);
    ushort_t h, l;
    split_bf16(v.x, h, l);
    dst[idx] = h;
    dst[idx + 65536] = l;
    split_bf16(v.y, h, l);
    dst[idx + 131072] = h;
    dst[idx + 196608] = l;
  }
}

// ---------------- coupled Newton step ----------------
__global__ __launch_bounds__(256) void k_newt_step(const float2* __restrict__ Xin,
                                                   const float2* __restrict__ Ein,
                                                   float2* __restrict__ Xout,
                                                   float2* __restrict__ Eout, int xblocks) {
  __shared__ float2 As[16][17], Bs[16][17];
  int bid = blockIdx.x;
  bool isX = bid < xblocks;
  int b = isX ? bid : bid - xblocks;
  const float2* Bm = isX ? Xin : Ein;
  int i0 = (b >> 4) * 16, j0 = (b & 15) * 16;
  int tx = threadIdx.x & 15, ty = threadIdx.x >> 4;
  float accx = 0.f, accy = 0.f;
  for (int k0 = 0; k0 < 256; k0 += 16) {
    __syncthreads();
    As[ty][tx] = Ein[(i0 + ty) * 256 + k0 + tx];
    Bs[ty][tx] = Bm[(k0 + ty) * 256 + j0 + tx];
    __syncthreads();
#pragma unroll
    for (int kk = 0; kk < 16; ++kk) {
      float2 a = As[ty][kk], bb = Bs[kk][tx];
      accx += a.x * bb.x - a.y * bb.y;
      accy += a.x * bb.y + a.y * bb.x;
    }
  }
  int idx = (i0 + ty) * 256 + j0 + tx;
  if (isX) {
    float2 x = Xin[idx];
    Xout[idx] = make_float2(x.x + accx, x.y + accy);
  } else {
    Eout[idx] = make_float2(accx, accy);
  }
}

// ---------------- Newton final: X' = Xin + Ein@Xin -> split-bf16 planes ----------------
__global__ __launch_bounds__(256) void k_newt_fin(const float2* __restrict__ Xin,
                                                  const float2* __restrict__ Ein,
                                                  ushort_t* __restrict__ dst) {
  __shared__ float2 As[16][17], Bs[16][17];
  int b = blockIdx.x;
  int i0 = (b >> 4) * 16, j0 = (b & 15) * 16;
  int tx = threadIdx.x & 15, ty = threadIdx.x >> 4;
  float accx = 0.f, accy = 0.f;
  for (int k0 = 0; k0 < 256; k0 += 16) {
    __syncthreads();
    As[ty][tx] = Ein[(i0 + ty) * 256 + k0 + tx];
    Bs[ty][tx] = Xin[(k0 + ty) * 256 + j0 + tx];
    __syncthreads();
#pragma unroll
    for (int kk = 0; kk < 16; ++kk) {
      float2 a = As[ty][kk], bb = Bs[kk][tx];
      accx += a.x * bb.x - a.y * bb.y;
      accy += a.x * bb.y + a.y * bb.x;
    }
  }
  int idx = (i0 + ty) * 256 + j0 + tx;
  float2 x = Xin[idx];
  float vx = x.x + accx, vy = x.y + accy;
  ushort_t h, l;
  split_bf16(vx, h, l);
  dst[idx] = h;
  dst[idx + 65536] = l;
  split_bf16(vy, h, l);
  dst[idx + 131072] = h;
  dst[idx + 196608] = l;
}

// ---------------- wide MFMA (B LDS-staged): (256x256) @ (256x4096) ----------------
// mode 0: write W^T split-bf16 planes + d[l] atomics; mode 1: q[l] atomics
__global__ __launch_bounds__(256) void k_wide_mfma(const ushort_t* __restrict__ Ap,
                                                   const ushort_t* __restrict__ Bp,
                                                   const float* __restrict__ AuxRe,
                                                   const float* __restrict__ AuxIm,
                                                   ushort_t* __restrict__ WTout,
                                                   float* __restrict__ dq, int mode) {
  __shared__ __align__(16) ushort_t sB[4][64][40];
  const ushort_t* arh_p = Ap;
  const ushort_t* arl_p = Ap + 65536;
  const ushort_t* aih_p = Ap + 131072;
  const ushort_t* ail_p = Ap + 196608;
  const ushort_t* brh_p = Bp;
  const ushort_t* brl_p = Bp + 1048576;
  const ushort_t* bih_p = Bp + 2097152;
  const ushort_t* bil_p = Bp + 3145728;
  int j0 = blockIdx.x * 64;  // l
  int i0 = blockIdx.y * 64;  // m
  int tid = threadIdx.x;
  int lane = tid & 63, wv = tid >> 6;
  int srow = tid >> 2, sslot = tid & 3;
  int m = i0 + wv * 16 + (lane & 15);
  int kq = (lane >> 4) * 8;
  f32x4 z = {0.f, 0.f, 0.f, 0.f};
  f32x4 Zrr[4], Zri[4], Zir[4], Zii[4];
#pragma unroll
  for (int s = 0; s < 4; ++s) { Zrr[s] = z; Zri[s] = z; Zir[s] = z; Zii[s] = z; }
  for (int k0 = 0; k0 < 256; k0 += 32) {
    __syncthreads();
    {
      size_t bo = (size_t)(j0 + srow) * 256 + k0 + sslot * 8;
      *(bf16x8*)&sB[0][srow][sslot * 8] = *(const bf16x8*)(brh_p + bo);
      *(bf16x8*)&sB[1][srow][sslot * 8] = *(const bf16x8*)(brl_p + bo);
      *(bf16x8*)&sB[2][srow][sslot * 8] = *(const bf16x8*)(bih_p + bo);
      *(bf16x8*)&sB[3][srow][sslot * 8] = *(const bf16x8*)(bil_p + bo);
    }
    __syncthreads();
    size_t ao = (size_t)m * 256 + k0 + kq;
    bf16x8 arh = *(const bf16x8*)(arh_p + ao);
    bf16x8 arl = *(const bf16x8*)(arl_p + ao);
    bf16x8 aih = *(const bf16x8*)(aih_p + ao);
    bf16x8 ail = *(const bf16x8*)(ail_p + ao);
#pragma unroll
    for (int s = 0; s < 4; ++s) {
      int brow = s * 16 + (lane & 15);
      bf16x8 brh = *(const bf16x8*)&sB[0][brow][kq];
      bf16x8 brl = *(const bf16x8*)&sB[1][brow][kq];
      bf16x8 bih = *(const bf16x8*)&sB[2][brow][kq];
      bf16x8 bil = *(const bf16x8*)&sB[3][brow][kq];
      MFMA3(Zrr[s], arh, arl, brh, brl);
      MFMA3(Zri[s], arh, arl, bih, bil);
      MFMA3(Zir[s], aih, ail, brh, brl);
      MFMA3(Zii[s], aih, ail, bih, bil);
    }
  }
  int rbase = i0 + wv * 16 + (lane >> 4) * 4;
#pragma unroll
  for (int s = 0; s < 4; ++s) {
    int col = j0 + s * 16 + (lane & 15);
    size_t wo = (size_t)col * 256 + rbase;
    float part = 0.f;
    if (mode == 0) {
      us4 hr, lr, hi, li;
#pragma unroll
      for (int r = 0; r < 4; ++r) {
        float re = Zrr[s][r] - Zii[s][r];   // a * b
        float im = Zri[s][r] + Zir[s][r];
        ushort_t h, l;
        split_bf16(re, h, l);
        hr[r] = h; lr[r] = l;
        split_bf16(im, h, l);
        hi[r] = h; li[r] = l;
        size_t o = (size_t)(rbase + r) * LL + col;
        part += re * AuxRe[o] - im * AuxIm[o];
      }
      *(us4*)(WTout + wo) = hr;
      *(us4*)(WTout + 1048576 + wo) = lr;
      *(us4*)(WTout + 2097152 + wo) = hi;
      *(us4*)(WTout + 3145728 + wo) = li;
    } else {
      us4 wh = *(const us4*)(brh_p + wo);
      us4 wl = *(const us4*)(brl_p + wo);
      us4 wih = *(const us4*)(bih_p + wo);
      us4 wil = *(const us4*)(bil_p + wo);
#pragma unroll
      for (int r = 0; r < 4; ++r) {
        float re = Zrr[s][r] - Zii[s][r];
        float im = Zri[s][r] + Zir[s][r];
        float wx = bfu2f(wh[r]) + bfu2f(wl[r]);
        float wy = bfu2f(wih[r]) + bfu2f(wil[r]);
        part += wx * re + wy * im;
      }
    }
    part += __shfl_down(part, 32);
    part += __shfl_down(part, 16);
    if ((lane >> 4) == 0) atomicAdd(dq + col, part);
  }
}

// ---------------- fused: per-row LN-stats recompute + gate + attention + combine --------
__global__ __launch_bounds__(256) void k_gateattn(const float* __restrict__ ws,
                                                  const float* __restrict__ Wg,
                                                  const float* __restrict__ gb,
                                                  const float* __restrict__ inw,
                                                  const float* __restrict__ inb,
                                                  const float* __restrict__ outw,
                                                  const float* __restrict__ outb,
                                                  const float* __restrict__ gamma,
                                                  const float* __restrict__ delta,
                                                  const float* __restrict__ lnw,
                                                  const float* __restrict__ lnb,
                                                  const float* __restrict__ lmbda,
                                                  float* __restrict__ out) {
  const float4* q4 = (const float4*)(ws + OFF_Q);
  const float4* d4 = (const float4*)(ws + OFF_D);
  const float4* g4 = (const float4*)gamma;
  const float4* lw4 = (const float4*)lnw;
  const float4* lb4 = (const float4*)lnb;
  int i = blockIdx.x, tid = threadIdx.x;
  float dlt = 1.0f / (1.0f + expf(-delta[0]));
  float s = 0.f;
  for (int j = tid; j < LL / 4; j += 256) {
    float4 qv = q4[j], dv = d4[j], pv = g4[j];
    s += pv.x + dlt * (qv.x / (dv.x + 1e-12f) - pv.x);
    s += pv.y + dlt * (qv.y / (dv.y + 1e-12f) - pv.y);
    s += pv.z + dlt * (qv.z / (dv.z + 1e-12f) - pv.z);
    s += pv.w + dlt * (qv.w / (dv.w + 1e-12f) - pv.w);
  }
  float mu = blk_red_sum(s) * (1.0f / LL);
  float s2 = 0.f;
  for (int j = tid; j < LL / 4; j += 256) {
    float4 qv = q4[j], dv = d4[j], pv = g4[j];
    float u0 = pv.x + dlt * (qv.x / (dv.x + 1e-12f) - pv.x) - mu;
    float u1 = pv.y + dlt * (qv.y / (dv.y + 1e-12f) - pv.y) - mu;
    float u2 = pv.z + dlt * (qv.z / (dv.z + 1e-12f) - pv.z) - mu;
    float u3 = pv.w + dlt * (qv.w / (dv.w + 1e-12f) - pv.w) - mu;
    s2 += u0 * u0 + u1 * u1 + u2 * u2 + u3 * u3;
  }
  float var = blk_red_sum(s2) * (1.0f / LL);
  float inv = rsqrtf(var + 1e-5f);
  const float* qs = ws + OFF_Q;
  const float* ds = ws + OFF_D;
  float v_i = qs[i] / (ds[i] + 1e-12f);
  float u_i = gamma[i] + dlt * (v_i - gamma[i]);
  float up_i = (u_i - mu) * inv * lnw[i] + lnb[i];
  float qvv = up_i * inw[0] + inb[0];
  float w1 = inw[1], b1 = inb[1], w2 = inw[2], b2 = inb[2];
  const float4* wr = (const float4*)(Wg + (size_t)i * LL);
  float sdot = 0.f, mx = -3.4e38f;
  for (int j = tid; j < LL / 4; j += 256) {
    float4 qv = q4[j], dv = d4[j], pv = g4[j], w = wr[j], lwv = lw4[j], lbv = lb4[j];
    float u0 = pv.x + dlt * (qv.x / (dv.x + 1e-12f) - pv.x);
    float u1 = pv.y + dlt * (qv.y / (dv.y + 1e-12f) - pv.y);
    float u2 = pv.z + dlt * (qv.z / (dv.z + 1e-12f) - pv.z);
    float u3 = pv.w + dlt * (qv.w / (dv.w + 1e-12f) - pv.w);
    sdot += w.x * u0 + w.y * u1 + w.z * u2 + w.w * u3;
    float k0 = ((u0 - mu) * inv * lwv.x + lbv.x) * w1 + b1;
    float k1 = ((u1 - mu) * inv * lwv.y + lbv.y) * w1 + b1;
    float k2 = ((u2 - mu) * inv * lwv.z + lbv.z) * w1 + b1;
    float k3 = ((u3 - mu) * inv * lwv.w + lbv.w) * w1 + b1;
    mx = fmaxf(mx, fmaxf(fmaxf(qvv * k0, qvv * k1), fmaxf(qvv * k2, qvv * k3)));
  }
  float tot = blk_red_sum(sdot);
  mx = blk_red_max(mx);
  float g = 1.0f / (1.0f + expf(-(tot + gb[i])));
  float den = 0.f, num = 0.f;
  for (int j = tid; j < LL / 4; j += 256) {
    float4 qv = q4[j], dv = d4[j], pv = g4[j], lwv = lw4[j], lbv = lb4[j];
    float u0 = pv.x + dlt * (qv.x / (dv.x + 1e-12f) - pv.x);
    float u1 = pv.y + dlt * (qv.y / (dv.y + 1e-12f) - pv.y);
    float u2 = pv.z + dlt * (qv.z / (dv.z + 1e-12f) - pv.z);
    float u3 = pv.w + dlt * (qv.w / (dv.w + 1e-12f) - pv.w);
    float p0 = (u0 - mu) * inv * lwv.x + lbv.x;
    float p1 = (u1 - mu) * inv * lwv.y + lbv.y;
    float p2 = (u2 - mu) * inv * lwv.z + lbv.z;
    float p3 = (u3 - mu) * inv * lwv.w + lbv.w;
    float e0 = expf(qvv * (p0 * w1 + b1) - mx);
    float e1 = expf(qvv * (p1 * w1 + b1) - mx);
    float e2 = expf(qvv * (p2 * w1 + b1) - mx);
    float e3 = expf(qvv * (p3 * w1 + b1) - mx);
    den += e0 + e1 + e2 + e3;
    num += e0 * (p0 * w2 + b2) + e1 * (p1 * w2 + b2) + e2 * (p2 * w2 + b2) + e3 * (p3 * w2 + b2);
  }
  den = blk_red_sum(den);
  num = blk_red_sum(num);
  if (tid == 0) {
    float attn = (num / den) * outw[0] + outb[0];
    float r = g * v_i + (1.0f - g) * gamma[i] + attn - lmbda[0];
    out[i] = fmaxf(r, 0.0f);
  }
}

extern "C" void kernel_launch(void* const* d_in, const int* in_sizes, int n_in,
                              void* d_out, int out_size, void* d_ws, size_t ws_size,
                              hipStream_t stream) {
  const float* gamma = (const float*)d_in[0];
  const float* Are   = (const float*)d_in[1];
  const float* Aim   = (const float*)d_in[2];
  const float* Xre   = (const float*)d_in[3];
  const float* Xim   = (const float*)d_in[4];
  const float* lnw   = (const float*)d_in[5];
  const float* lnb   = (const float*)d_in[6];
  const float* inw   = (const float*)d_in[7];
  const float* inb   = (const float*)d_in[8];
  const float* outw  = (const float*)d_in[9];
  const float* outb  = (const float*)d_in[10];
  const float* gateW = (const float*)d_in[11];
  const float* gateb = (const float*)d_in[12];
  const float* delta = (const float*)d_in[13];
  const float* lmbda = (const float*)d_in[14];
  float* out = (float*)d_out;
  float* ws = (float*)d_ws;

  float2* XA = (float2*)(ws + OFF_XA);
  float2* XB = (float2*)(ws + OFF_XB);
  float2* EA = (float2*)(ws + OFF_EA);
  float2* EB = (float2*)(ws + OFF_EB);
  ushort_t* Rinvp = (ushort_t*)(ws + OFF_RINVP);

  k_prep<<<3616, 256, 0, stream>>>(ws, Are, Aim, Xre, Xim, gamma);
  k_gram_both<<<480, 256, 0, stream>>>(ws);
  k_n1<<<768, 256, 0, stream>>>(ws);
  k_newt_step<<<512, 256, 0, stream>>>(XA, EA, XB, EB, 256);      // X2, E2=E0^4
  k_newt_step<<<512, 256, 0, stream>>>(XB, EB, XA, EA, 256);      // X3, E3=E0^8
  k_newt_step<<<512, 256, 0, stream>>>(XA, EA, XB, EB, 256);      // X4, E4=E0^16
  k_newt_fin<<<256, 256, 0, stream>>>(XB, EB, Rinvp);             // X5 -> planes

  k_wide_mfma<<<dim3(64, 4), 256, 0, stream>>>(Rinvp, (ushort_t*)(ws + OFF_ATP),
                                               Are, Aim, (ushort_t*)(ws + OFF_WTP),
                                               ws + OFF_D, 0);
  k_wide_mfma<<<dim3(64, 4), 256, 0, stream>>>((ushort_t*)(ws + OFF_GP),
                                               (ushort_t*)(ws + OFF_WTP),
                                               nullptr, nullptr, nullptr, ws + OFF_Q, 1);
  k_gateattn<<<LL, 256, 0, stream>>>(ws, gateW, gateb, inw, inb, outw, outb,
                                     gamma, delta, lnw, lnb, lmbda, out);
}